// Round 2
// baseline (741.320 us; speedup 1.0000x reference)
//
#include <hip/hip_runtime.h>
#include <hip/hip_bf16.h>

// TriDirectionalMamba: C=96, L=32, DI=192, N_STATE=16, DT_RANK=6, D_CONV=4
// One block = one (direction, sequence). 3*1024 = 3072 blocks, 256 threads.

#define EPS_ 1e-5f

struct __align__(16) Smem {
    union {                       // region A: lifetimes disjoint
        float aT[96 * 36];        // LN'ed input, col-major [c][t], stride 36 (16B-aligned rows)
        float xd[32 * 41];        // x_dbl [t][38] stride 41 (bank-friendly)
    } ra;                         // 13824 B
    union {                       // region B: lifetimes disjoint
        float xm[32 * 192];       // pre-conv xm [t][d]
        float dT[192 * 36];       // delta, then y_total, col-major [d][t] stride 36
    } rb;                         // 27648 B
    float uT[192 * 36];           // silu(conv(xm)) col-major [d][t] stride 36  27648 B
    __hip_bfloat16 res[32 * 192]; // silu(res) gate [t][d]                     12288 B
};                                // total 81408 B -> 2 blocks/CU on gfx950

__device__ __forceinline__ float silu_f(float v) { return v / (1.f + __expf(-v)); }

__global__ __launch_bounds__(256) void tdm_kernel(
    const float* __restrict__ x,     const float* __restrict__ ln_g,  const float* __restrict__ ln_b,
    const float* __restrict__ Win,   const float* __restrict__ Wconv, const float* __restrict__ bconv,
    const float* __restrict__ Wxp,   const float* __restrict__ Wdt,   const float* __restrict__ bdt,
    const float* __restrict__ A_log, const float* __restrict__ Dskip, const float* __restrict__ Wout,
    const float* __restrict__ alpha, float* __restrict__ out)
{
    __shared__ Smem sm;
    const int tid = threadIdx.x;
    const int bid = blockIdx.x;
    const int dir = bid >> 10;      // 0: scan over D, 1: over H, 2: over W
    const int s   = bid & 1023;

    const float* gi = ln_g  + dir * 96;
    const float* bi = ln_b  + dir * 96;
    const float* Wi = Win   + dir * 96 * 384;
    const float* Wc = Wconv + dir * 192 * 4;
    const float* bc = bconv + dir * 192;
    const float* Wx = Wxp   + dir * 192 * 38;
    const float* Wd = Wdt   + dir * 6 * 192;
    const float* bd = bdt   + dir * 192;
    const float* Al = A_log + dir * 192 * 16;
    const float* Dk = Dskip + dir * 192;
    const float* Wo = Wout  + dir * 192 * 96;

    // element (c, t) of this sequence lives at x[c*32768 + t*tmul + base0]
    int base0, tmul;
    {
        const int hi = s >> 5, lo = s & 31;
        if (dir == 0)      { base0 = hi * 32 + lo;        tmul = 1024; } // seq = (h,w), t = d
        else if (dir == 1) { base0 = hi * 1024 + lo;      tmul = 32;   } // seq = (d,w), t = h
        else               { base0 = hi * 1024 + lo * 32; tmul = 1;    } // seq = (d,h), t = w
    }

    // ---------- Phase 0: gather + LayerNorm -> aT[c][t] ----------
    {
        const int row = tid >> 3;   // t, 0..31
        const int sub = tid & 7;    // 8 threads per row, 12 channels each
        float xv[12];
        float sum = 0.f, sq = 0.f;
        #pragma unroll
        for (int j = 0; j < 12; ++j) {
            const int c = sub * 12 + j;
            const float v = x[c * 32768 + row * tmul + base0];
            xv[j] = v; sum += v; sq += v * v;
        }
        #pragma unroll
        for (int m = 1; m < 8; m <<= 1) {
            sum += __shfl_xor(sum, m);
            sq  += __shfl_xor(sq, m);
        }
        const float mean = sum * (1.f / 96.f);
        const float var  = sq * (1.f / 96.f) - mean * mean;
        const float rstd = rsqrtf(var + EPS_);
        #pragma unroll
        for (int j = 0; j < 12; ++j) {
            const int c = sub * 12 + j;
            sm.ra.aT[c * 36 + row] = (xv[j] - mean) * rstd * gi[c] + bi[c];
        }
    }
    __syncthreads();

    const int rg = tid >> 5;   // row group: rows rg*4 .. rg*4+3
    const int cg = tid & 31;   // col group

    // ---------- Phase 1: GEMM1 (32x96)@(96x384); split xm | silu(res) ----------
    {
        float acc[4][12];
        #pragma unroll
        for (int r = 0; r < 4; ++r)
            #pragma unroll
            for (int c = 0; c < 12; ++c) acc[r][c] = 0.f;

        for (int k = 0; k < 96; ++k) {
            const float4 a4 = *(const float4*)&sm.ra.aT[k * 36 + rg * 4];
            const float aa[4] = {a4.x, a4.y, a4.z, a4.w};
            const float* bp = Wi + k * 384 + cg * 12;
            const float4 b0 = *(const float4*)(bp);
            const float4 b1 = *(const float4*)(bp + 4);
            const float4 b2 = *(const float4*)(bp + 8);
            const float bb[12] = {b0.x, b0.y, b0.z, b0.w, b1.x, b1.y, b1.z, b1.w,
                                  b2.x, b2.y, b2.z, b2.w};
            #pragma unroll
            for (int r = 0; r < 4; ++r)
                #pragma unroll
                for (int c = 0; c < 12; ++c) acc[r][c] += aa[r] * bb[c];
        }
        if (cg < 16) {   // xm half (cols 0..191)
            #pragma unroll
            for (int r = 0; r < 4; ++r)
                #pragma unroll
                for (int c = 0; c < 12; ++c)
                    sm.rb.xm[(rg * 4 + r) * 192 + cg * 12 + c] = acc[r][c];
        } else {         // res half (cols 192..383) -> silu -> bf16 gate
            #pragma unroll
            for (int r = 0; r < 4; ++r)
                #pragma unroll
                for (int c = 0; c < 12; ++c)
                    sm.res[(rg * 4 + r) * 192 + (cg - 16) * 12 + c] =
                        __float2bfloat16(silu_f(acc[r][c]));
        }
    }
    __syncthreads();

    // ---------- Phase 2: causal depthwise conv4 + silu -> uT[d][t] ----------
    #pragma unroll 4
    for (int it = 0; it < 24; ++it) {
        const int idx = it * 256 + tid;
        const int t = idx / 192;
        const int d = idx - t * 192;
        float acc = bc[d];
        #pragma unroll
        for (int k = 0; k < 4; ++k) {
            const int tt = t - 3 + k;
            if (tt >= 0) acc += sm.rb.xm[tt * 192 + d] * Wc[d * 4 + k];
        }
        sm.uT[d * 36 + t] = silu_f(acc);
    }
    __syncthreads();

    // ---------- Phase 3: GEMM2 (32x192)@(192x38) -> x_dbl ----------
    {
        float acc[4][2] = {{0.f, 0.f}, {0.f, 0.f}, {0.f, 0.f}, {0.f, 0.f}};
        const int j0 = cg, j1 = cg + 32;
        const bool v1 = (j1 < 38);
        for (int k = 0; k < 192; ++k) {
            const float4 a4 = *(const float4*)&sm.uT[k * 36 + rg * 4];
            const float b0 = Wx[k * 38 + j0];
            const float b1 = v1 ? Wx[k * 38 + j1] : 0.f;
            acc[0][0] += a4.x * b0; acc[0][1] += a4.x * b1;
            acc[1][0] += a4.y * b0; acc[1][1] += a4.y * b1;
            acc[2][0] += a4.z * b0; acc[2][1] += a4.z * b1;
            acc[3][0] += a4.w * b0; acc[3][1] += a4.w * b1;
        }
        #pragma unroll
        for (int r = 0; r < 4; ++r) {
            sm.ra.xd[(rg * 4 + r) * 41 + j0] = acc[r][0];
            if (v1) sm.ra.xd[(rg * 4 + r) * 41 + j1] = acc[r][1];
        }
    }
    __syncthreads();

    // ---------- Phase 4: delta = softplus(dt @ Wdt + bdt) -> dT[d][t] ----------
    #pragma unroll 4
    for (int it = 0; it < 24; ++it) {
        const int idx = it * 256 + tid;
        const int t = idx / 192;
        const int d = idx - t * 192;
        float acc = bd[d];
        #pragma unroll
        for (int k = 0; k < 6; ++k) acc += sm.ra.xd[t * 41 + k] * Wd[k * 192 + d];
        sm.rb.dT[d * 36 + t] = (acc > 20.f) ? acc : log1pf(__expf(acc));
    }
    __syncthreads();

    // ---------- Phase 5: selective scan, one thread per channel ----------
    if (tid < 192) {
        const int d = tid;
        float A[16];
        #pragma unroll
        for (int n = 0; n < 16; ++n) A[n] = -__expf(Al[d * 16 + n]);
        const float dsk = Dk[d];
        float st[16];
        #pragma unroll
        for (int n = 0; n < 16; ++n) st[n] = 0.f;
        for (int t = 0; t < 32; ++t) {
            const float dlt = sm.rb.dT[d * 36 + t];
            const float ut  = sm.uT[d * 36 + t];
            const float du  = dlt * ut;
            float y = 0.f;
            #pragma unroll
            for (int n = 0; n < 16; ++n) {
                const float dA = __expf(dlt * A[n]);
                st[n] = dA * st[n] + du * sm.ra.xd[t * 41 + 6 + n];
                y += st[n] * sm.ra.xd[t * 41 + 22 + n];
            }
            const float gate = __bfloat162float(sm.res[t * 192 + d]);
            sm.rb.dT[d * 36 + t] = (y + ut * dsk) * gate;  // y_total, in place
        }
    }
    __syncthreads();

    // ---------- Phase 6: GEMM3 (32x192)@(192x96), scale by softmax(alpha), scatter ----------
    {
        float acc[4][3] = {{0.f,0.f,0.f},{0.f,0.f,0.f},{0.f,0.f,0.f},{0.f,0.f,0.f}};
        for (int k = 0; k < 192; ++k) {
            const float4 a4 = *(const float4*)&sm.rb.dT[k * 36 + rg * 4];
            const float b0 = Wo[k * 96 + cg];
            const float b1 = Wo[k * 96 + cg + 32];
            const float b2 = Wo[k * 96 + cg + 64];
            acc[0][0] += a4.x * b0; acc[0][1] += a4.x * b1; acc[0][2] += a4.x * b2;
            acc[1][0] += a4.y * b0; acc[1][1] += a4.y * b1; acc[1][2] += a4.y * b2;
            acc[2][0] += a4.z * b0; acc[2][1] += a4.z * b1; acc[2][2] += a4.z * b2;
            acc[3][0] += a4.w * b0; acc[3][1] += a4.w * b1; acc[3][2] += a4.w * b2;
        }
        const float e0 = __expf(alpha[0]), e1 = __expf(alpha[1]), e2 = __expf(alpha[2]);
        const float w = ((dir == 0) ? e0 : (dir == 1) ? e1 : e2) / (e0 + e1 + e2);
        #pragma unroll
        for (int r = 0; r < 4; ++r) {
            const int t = rg * 4 + r;
            #pragma unroll
            for (int c = 0; c < 3; ++c) {
                const int j = cg + c * 32;
                atomicAdd(&out[j * 32768 + t * tmul + base0], acc[r][c] * w);
            }
        }
    }
}

extern "C" void kernel_launch(void* const* d_in, const int* in_sizes, int n_in,
                              void* d_out, int out_size, void* d_ws, size_t ws_size,
                              hipStream_t stream) {
    (void)in_sizes; (void)n_in; (void)d_ws; (void)ws_size;
    hipMemsetAsync(d_out, 0, (size_t)out_size * sizeof(float), stream);
    tdm_kernel<<<dim3(3072), dim3(256), 0, stream>>>(
        (const float*)d_in[0],  (const float*)d_in[1],  (const float*)d_in[2],
        (const float*)d_in[3],  (const float*)d_in[4],  (const float*)d_in[5],
        (const float*)d_in[6],  (const float*)d_in[7],  (const float*)d_in[8],
        (const float*)d_in[9],  (const float*)d_in[10], (const float*)d_in[11],
        (const float*)d_in[12], (float*)d_out);
}